// Round 7
// baseline (1073.137 us; speedup 1.0000x reference)
//
#include <hip/hip_runtime.h>

#define NN 100000
#define EE 1600000
#define TOT (EE + NN)
#define NEG 0.2f
#define NB 256                      // dst buckets (one fine-block each)
#define CH 391                      // nodes per bucket = ceil(NN/NB)
#define TILE 4096                   // edges per bin block
#define NTILES ((EE + TILE - 1) / TILE)   // 391
#define GEMM_BLKS ((NN + 63) / 64)  // 1563 (gat_g2 tiles of 64)
#define GEMM1_BLKS (NN / 32)        // 3125 (32 rows/block, exact: no tail)
#define LDA 132                     // LDS row stride (floats): 16B-aligned

typedef unsigned int uint;
typedef unsigned short ushort;

#define BLO(u) __uint_as_float((u) << 16)
#define BHI(u) __uint_as_float((u) & 0xffff0000u)

__device__ inline ushort f2bf(float f) {            // RNE f32 -> bf16
    uint u = __float_as_uint(f);
    return (ushort)((u + 0x7fff + ((u >> 16) & 1)) >> 16);
}

__device__ inline int imin(int a, int b) { return a < b ? a : b; }

// ---------------- bucket count ----------------

__launch_bounds__(256) __global__
void k_bcount(const int* __restrict__ dst, int* __restrict__ bcnt) {
    __shared__ int h[NB];
    int t = threadIdx.x;
    h[t] = 0;
    __syncthreads();
    int base = blockIdx.x * TILE;
#pragma unroll
    for (int r = 0; r < 16; ++r) {
        int e = base + r * 256 + t;
        if (e < EE) atomicAdd(&h[dst[e] / CH], 1);
    }
    __syncthreads();
    if (h[t]) atomicAdd(&bcnt[t], h[t]);
}

// ---------------- bucket prefix (1 block) ----------------

__launch_bounds__(NB) __global__
void k_bprefix(const int* __restrict__ bcnt, int* __restrict__ boff,
               int* __restrict__ bcsr, int* __restrict__ bfill) {
    __shared__ int s1[NB], s2[NB];
    int t = threadIdx.x;
    int c = bcnt[t];
    int nb0 = t * CH;
    int nib = imin(nb0 + CH, NN) - nb0;     // nodes in this bucket
    s1[t] = c; s2[t] = c + nib;
    __syncthreads();
    for (int off = 1; off < NB; off <<= 1) {
        int a = (t >= off) ? s1[t - off] : 0;
        int b = (t >= off) ? s2[t - off] : 0;
        __syncthreads();
        s1[t] += a; s2[t] += b;
        __syncthreads();
    }
    int ex = s1[t] - c;
    boff[t] = ex;
    bfill[t] = ex;
    bcsr[t] = s2[t] - (c + nib);
    if (t == NB - 1) boff[NB] = EE;
}

// ---------------- bin pass: LDS multi-split, coalesced global writes --------

__launch_bounds__(256) __global__
void k_bin(const int* __restrict__ src, const int* __restrict__ dst,
           const float* __restrict__ ew, int* __restrict__ bfill,
           long long* __restrict__ binned) {
    __shared__ long long recs[TILE];   // 32 KB, bucket-ordered staging
    __shared__ ushort    bkt[TILE];    // 8 KB
    __shared__ int hist[NB], eoff[NB], gbase[NB];
    int t = threadIdx.x;
    hist[t] = 0;
    __syncthreads();
    int base = blockIdx.x * TILE;
    int cnt = imin(TILE, EE - base);
    long long rec[16]; int binfo[16];
#pragma unroll
    for (int r = 0; r < 16; ++r) {
        int i = r * 256 + t;
        if (i < cnt) {
            int e = base + i;
            int s = src[e], d = dst[e];
            float w = ew[e];
            int b = d / CH;
            int ldst = d - b * CH;
            int rk = atomicAdd(&hist[b], 1);          // LDS atomic = within-tile rank
            rec[r] = (long long)(uint)(s | (ldst << 17)) |
                     ((long long)__float_as_uint(w) << 32);
            binfo[r] = b | (rk << 8);
        }
    }
    __syncthreads();
    int c = hist[t];
    eoff[t] = c;
    __syncthreads();
    for (int off = 1; off < NB; off <<= 1) {          // inclusive scan
        int a = (t >= off) ? eoff[t - off] : 0;
        __syncthreads();
        eoff[t] += a;
        __syncthreads();
    }
    int ex = eoff[t] - c;                             // own exclusive offset
    gbase[t] = atomicAdd(&bfill[t], c);               // reserve contiguous chunk
    eoff[t] = ex;
    __syncthreads();
#pragma unroll
    for (int r = 0; r < 16; ++r) {                    // stage bucket-ordered in LDS
        int i = r * 256 + t;
        if (i < cnt) {
            int b = binfo[r] & 255, rk = binfo[r] >> 8;
            int slot = eoff[b] + rk;
            recs[slot] = rec[r];
            bkt[slot] = (ushort)b;
        }
    }
    __syncthreads();
#pragma unroll
    for (int r = 0; r < 16; ++r) {                    // coalesced runs (~128B/bucket)
        int i = r * 256 + t;
        if (i < cnt) {
            int b = bkt[i];
            binned[gbase[b] + (i - eoff[b])] = recs[i];
        }
    }
}

// ---------------- gemm1 body: col-seg-per-lane mapping ----------------------
// thread t -> (row = bid*32 + t>>3, cols (t&7)*16..+16). W loads are per-lane
// float4 VMEM (L1-resident, 8-way broadcast, pipelined across k) instead of
// wave-uniform SGPR loads whose s_waitcnt serialized each 32-FMA burst.
// Per-output k-ascending fmaf chain unchanged -> xp16 bit-identical.
// Stores: 8 lanes cover a full 256B row, fully coalesced.

__device__ __forceinline__ void gemm1_body(
    int bid, const float* __restrict__ A, const float* __restrict__ W,
    ushort* __restrict__ C16, const float* __restrict__ att_s,
    const float* __restrict__ att_d, float* __restrict__ a_s,
    float* __restrict__ a_d) {
    int t = threadIdx.x;
    int row = bid * 32 + (t >> 3);          // 3125*32 == NN: no tail
    int cseg = t & 7, c0 = cseg * 16;
    const float* __restrict__ a = A + (size_t)row * 128;
    const float* __restrict__ wp = W + c0;
    float acc[16];
#pragma unroll
    for (int c = 0; c < 16; ++c) acc[c] = 0.f;
#pragma unroll 2
    for (int k = 0; k < 128; k += 4) {
        float4 av = *(const float4*)(a + k);
        float xs[4] = {av.x, av.y, av.z, av.w};
#pragma unroll
        for (int kk = 0; kk < 4; ++kk) {
            const float* wr = wp + (k + kk) * 128;
            float4 w0 = *(const float4*)(wr +  0);
            float4 w1 = *(const float4*)(wr +  4);
            float4 w2 = *(const float4*)(wr +  8);
            float4 w3 = *(const float4*)(wr + 12);
            float xk = xs[kk];
            acc[ 0]=fmaf(xk,w0.x,acc[ 0]); acc[ 1]=fmaf(xk,w0.y,acc[ 1]);
            acc[ 2]=fmaf(xk,w0.z,acc[ 2]); acc[ 3]=fmaf(xk,w0.w,acc[ 3]);
            acc[ 4]=fmaf(xk,w1.x,acc[ 4]); acc[ 5]=fmaf(xk,w1.y,acc[ 5]);
            acc[ 6]=fmaf(xk,w1.z,acc[ 6]); acc[ 7]=fmaf(xk,w1.w,acc[ 7]);
            acc[ 8]=fmaf(xk,w2.x,acc[ 8]); acc[ 9]=fmaf(xk,w2.y,acc[ 9]);
            acc[10]=fmaf(xk,w2.z,acc[10]); acc[11]=fmaf(xk,w2.w,acc[11]);
            acc[12]=fmaf(xk,w3.x,acc[12]); acc[13]=fmaf(xk,w3.y,acc[13]);
            acc[14]=fmaf(xk,w3.z,acc[14]); acc[15]=fmaf(xk,w3.w,acc[15]);
        }
    }
    ushort* o = C16 + (size_t)row * 128 + c0;
    uint4 p;
    p.x = (uint)f2bf(acc[ 0]) | ((uint)f2bf(acc[ 1]) << 16);
    p.y = (uint)f2bf(acc[ 2]) | ((uint)f2bf(acc[ 3]) << 16);
    p.z = (uint)f2bf(acc[ 4]) | ((uint)f2bf(acc[ 5]) << 16);
    p.w = (uint)f2bf(acc[ 6]) | ((uint)f2bf(acc[ 7]) << 16);
    *(uint4*)(o) = p;
    p.x = (uint)f2bf(acc[ 8]) | ((uint)f2bf(acc[ 9]) << 16);
    p.y = (uint)f2bf(acc[10]) | ((uint)f2bf(acc[11]) << 16);
    p.z = (uint)f2bf(acc[12]) | ((uint)f2bf(acc[13]) << 16);
    p.w = (uint)f2bf(acc[14]) | ((uint)f2bf(acc[15]) << 16);
    *(uint4*)(o + 8) = p;
    // logit epilogue: head = cseg>>1; pair (cseg, cseg^1) holds the 32 cols
    int head = cseg >> 1;
    const float* as = att_s + head * 32 + (cseg & 1) * 16;
    const float* ad = att_d + head * 32 + (cseg & 1) * 16;
    float s0 = 0.f, s1 = 0.f;
#pragma unroll
    for (int j = 0; j < 16; ++j) {
        s0 = fmaf(acc[j], as[j], s0);
        s1 = fmaf(acc[j], ad[j], s1);
    }
    s0 += __shfl_xor(s0, 1);
    s1 += __shfl_xor(s1, 1);
    if ((cseg & 1) == 0) {
        a_s[row * 4 + head] = s0;
        a_d[row * 4 + head] = s1;
    }
}

// ---------------- fused: fine scatter (L2-resident per bucket) + gemm1 ------

__launch_bounds__(256) __global__
void k_fine_gemm(const long long* __restrict__ binned, const int* __restrict__ boff,
                 const int* __restrict__ bcsr, int* __restrict__ row_off,
                 long long* __restrict__ csr,
                 const float* __restrict__ A, const float* __restrict__ W,
                 ushort* __restrict__ C16, const float* __restrict__ att_s,
                 const float* __restrict__ att_d, float* __restrict__ a_s,
                 float* __restrict__ a_d) {
    if (blockIdx.x >= NB) {
        gemm1_body(blockIdx.x - NB, A, W, C16, att_s, att_d, a_s, a_d);
        return;
    }
    __shared__ int hist[CH];
    __shared__ int excl[CH];
    __shared__ int sc[512];
    int t = threadIdx.x;
    int b = blockIdx.x;
    int e0 = boff[b], e1 = boff[b + 1];
    int nb0 = b * CH;
    int nnode = imin(CH, NN - nb0);
    const int2* __restrict__ bn = (const int2*)binned;
    hist[t] = 0;
    if (t + 256 < CH) hist[t + 256] = 0;
    __syncthreads();
    for (int i = e0 + t; i < e1; i += 256)            // pass 1: per-node counts
        atomicAdd(&hist[bn[i].x >> 17], 1);
    __syncthreads();
    int v0 = (t < nnode) ? hist[t] + 1 : 0;           // +1 self-loop
    int v1 = (t + 256 < nnode) ? hist[t + 256] + 1 : 0;
    sc[t] = v0; sc[t + 256] = v1;
    __syncthreads();
    for (int off = 1; off < 512; off <<= 1) {         // Hillis-Steele, 2 elems/thread
        int a0 = (t >= off) ? sc[t - off] : 0;
        int a1 = (t + 256 >= off) ? sc[t + 256 - off] : 0;
        __syncthreads();
        sc[t] += a0; sc[t + 256] += a1;
        __syncthreads();
    }
    int csr0 = bcsr[b];
    if (t < nnode) {
        excl[t] = csr0 + sc[t] - v0;
        row_off[nb0 + t] = excl[t];
    }
    if (t + 256 < nnode) {
        excl[t + 256] = csr0 + sc[t + 256] - v1;
        row_off[nb0 + t + 256] = excl[t + 256];
    }
    if (b == 0 && t == 0) row_off[NN] = TOT;
    hist[t] = 0;                                      // reset -> rank counters
    if (t + 256 < CH) hist[t + 256] = 0;
    __syncthreads();
    for (int i = e0 + t; i < e1; i += 256) {          // pass 2: L2-window scatter
        int2 r = bn[i];
        int ld = r.x >> 17;
        int rk = atomicAdd(&hist[ld], 1);
        long long rec = (long long)(uint)(r.x & 0x1FFFF) |
                        ((long long)(uint)r.y << 32);
        csr[excl[ld] + rk] = rec;
    }
    __syncthreads();
    for (int i = t; i < nnode; i += 256) {            // self-loops at row end, w = 1
        int n = nb0 + i;
        csr[excl[i] + hist[i]] = (long long)(uint)n | (0x3F800000LL << 32);
    }
}

// ---------------- fused GAT aggregation + GEMM2 (512-thread blocks) ----------
// Phase 1: round-5 structure (best measured gather config for the fusion).
// Phase 2: col-seg-per-lane GEMM (see gemm1_body comment); full-line h16 writes.

__launch_bounds__(512) __global__
void k_gat_g2(const int* __restrict__ row_off, const int2* __restrict__ csr,
              const float* __restrict__ a_s, const float* __restrict__ a_d,
              const ushort* __restrict__ xp16, const float* __restrict__ W,
              ushort* __restrict__ h16, float* __restrict__ dinv) {
    __shared__ float As[64 * LDA];
    __shared__ float sdinv[64];
    int lane = threadIdx.x & 63;
    int wv = threadIdx.x >> 6;              // 0..7
    int grp = lane >> 4, sl = lane & 15, h2 = sl >> 2;
    int nbase = blockIdx.x * 64;

    for (int rnd = 0; rnd < 8; ++rnd) {
        int r = (rnd << 3) | wv;            // row in block, 0..63
        int node = nbase + r;
        if (node < NN) {
            int base = row_off[node], end = row_off[node + 1];
            float adh = a_d[node * 4 + h2];
            float acc[8];
#pragma unroll
            for (int j = 0; j < 8; ++j) acc[j] = 0.f;
            float den = 0.f, wsum = 0.f;
            int na = end - 1;
            int i0 = base + grp;
            int2 e0v = csr[imin(i0,      na)];
            int2 e1v = csr[imin(i0 + 4,  na)];
            int2 e2v = csr[imin(i0 + 8,  na)];
            int2 e3v = csr[imin(i0 + 12, na)];
            for (int i = i0; i < end; i += 16) {
                int2 p0 = csr[imin(i + 16, na)];        // prefetch next trip
                int2 p1 = csr[imin(i + 20, na)];
                int2 p2 = csr[imin(i + 24, na)];
                int2 p3 = csr[imin(i + 28, na)];
                uint4 q0 = *(const uint4*)(xp16 + (size_t)e0v.x * 128 + sl * 8);
                uint4 q1 = *(const uint4*)(xp16 + (size_t)e1v.x * 128 + sl * 8);
                uint4 q2 = *(const uint4*)(xp16 + (size_t)e2v.x * 128 + sl * 8);
                uint4 q3 = *(const uint4*)(xp16 + (size_t)e3v.x * 128 + sl * 8);
                float al0 = a_s[e0v.x * 4 + h2] + adh;
                float al1 = a_s[e1v.x * 4 + h2] + adh;
                float al2 = a_s[e2v.x * 4 + h2] + adh;
                float al3 = a_s[e3v.x * 4 + h2] + adh;
                al0 = al0 > 0.f ? al0 : NEG * al0;
                al1 = al1 > 0.f ? al1 : NEG * al1;
                al2 = al2 > 0.f ? al2 : NEG * al2;
                al3 = al3 > 0.f ? al3 : NEG * al3;
                float aw0 = __expf(al0);                     // i < end always
                float aw1 = (i + 4  < end) ? __expf(al1) : 0.f;
                float aw2 = (i + 8  < end) ? __expf(al2) : 0.f;
                float aw3 = (i + 12 < end) ? __expf(al3) : 0.f;
                float w0 = __int_as_float(e0v.y);
                float w1 = (i + 4  < end) ? __int_as_float(e1v.y) : 0.f;
                float w2 = (i + 8  < end) ? __int_as_float(e2v.y) : 0.f;
                float w3 = (i + 12 < end) ? __int_as_float(e3v.y) : 0.f;
                den  += (aw0 + aw1) + (aw2 + aw3);
                wsum += (w0 + w1) + (w2 + w3);
                acc[0] = fmaf(aw0, BLO(q0.x), fmaf(aw1, BLO(q1.x), fmaf(aw2, BLO(q2.x), fmaf(aw3, BLO(q3.x), acc[0]))));
                acc[1] = fmaf(aw0, BHI(q0.x), fmaf(aw1, BHI(q1.x), fmaf(aw2, BHI(q2.x), fmaf(aw3, BHI(q3.x), acc[1]))));
                acc[2] = fmaf(aw0, BLO(q0.y), fmaf(aw1, BLO(q1.y), fmaf(aw2, BLO(q2.y), fmaf(aw3, BLO(q3.y), acc[2]))));
                acc[3] = fmaf(aw0, BHI(q0.y), fmaf(aw1, BHI(q1.y), fmaf(aw2, BHI(q2.y), fmaf(aw3, BHI(q3.y), acc[3]))));
                acc[4] = fmaf(aw0, BLO(q0.z), fmaf(aw1, BLO(q1.z), fmaf(aw2, BLO(q2.z), fmaf(aw3, BLO(q3.z), acc[4]))));
                acc[5] = fmaf(aw0, BHI(q0.z), fmaf(aw1, BHI(q1.z), fmaf(aw2, BHI(q2.z), fmaf(aw3, BHI(q3.z), acc[5]))));
                acc[6] = fmaf(aw0, BLO(q0.w), fmaf(aw1, BLO(q1.w), fmaf(aw2, BLO(q2.w), fmaf(aw3, BLO(q3.w), acc[6]))));
                acc[7] = fmaf(aw0, BHI(q0.w), fmaf(aw1, BHI(q1.w), fmaf(aw2, BHI(q2.w), fmaf(aw3, BHI(q3.w), acc[7]))));
                e0v = p0; e1v = p1; e2v = p2; e3v = p3;
            }
#pragma unroll
            for (int j = 0; j < 8; ++j) {
                acc[j] += __shfl_xor(acc[j], 16);
                acc[j] += __shfl_xor(acc[j], 32);
            }
            den  += __shfl_xor(den, 16);   den  += __shfl_xor(den, 32);
            wsum += __shfl_xor(wsum, 16);  wsum += __shfl_xor(wsum, 32);
            if (grp == 0) {
                float il = 1.f / den;
                float* o = &As[r * LDA + sl * 8];
                *(float4*)(o)     = make_float4(acc[0]*il, acc[1]*il, acc[2]*il, acc[3]*il);
                *(float4*)(o + 4) = make_float4(acc[4]*il, acc[5]*il, acc[6]*il, acc[7]*il);
                if (sl == 0) {
                    float dv = rsqrtf(wsum);
                    sdinv[r] = dv;
                    dinv[node] = dv;        // k_gcn needs the dst-side factor
                }
            }
        } else if (grp == 0) {              // tail block: zero-fill invalid rows
            float* o = &As[r * LDA + sl * 8];
            *(float4*)(o)     = make_float4(0.f, 0.f, 0.f, 0.f);
            *(float4*)(o + 4) = make_float4(0.f, 0.f, 0.f, 0.f);
            if (sl == 0) sdinv[r] = 0.f;
        }
    }
    __syncthreads();

    // ---- phase 2: gemm2, col-seg per lane. thread t -> row t>>3, cols (t&7)*16 ----
    int tt = threadIdx.x;
    int r64 = tt >> 3, cseg = tt & 7, c0 = cseg * 16;
    int row = nbase + r64;
    bool valid = row < NN;
    const float* __restrict__ aL = &As[r64 * LDA];
    const float* __restrict__ wp = W + c0;
    float acc[16];
#pragma unroll
    for (int c = 0; c < 16; ++c) acc[c] = 0.f;
#pragma unroll 2
    for (int k = 0; k < 128; k += 4) {
        float4 av = *(const float4*)(aL + k);
        float xs[4] = {av.x, av.y, av.z, av.w};
#pragma unroll
        for (int kk = 0; kk < 4; ++kk) {
            const float* wr = wp + (k + kk) * 128;
            float4 w0 = *(const float4*)(wr +  0);
            float4 w1 = *(const float4*)(wr +  4);
            float4 w2 = *(const float4*)(wr +  8);
            float4 w3 = *(const float4*)(wr + 12);
            float xk = xs[kk];
            acc[ 0]=fmaf(xk,w0.x,acc[ 0]); acc[ 1]=fmaf(xk,w0.y,acc[ 1]);
            acc[ 2]=fmaf(xk,w0.z,acc[ 2]); acc[ 3]=fmaf(xk,w0.w,acc[ 3]);
            acc[ 4]=fmaf(xk,w1.x,acc[ 4]); acc[ 5]=fmaf(xk,w1.y,acc[ 5]);
            acc[ 6]=fmaf(xk,w1.z,acc[ 6]); acc[ 7]=fmaf(xk,w1.w,acc[ 7]);
            acc[ 8]=fmaf(xk,w2.x,acc[ 8]); acc[ 9]=fmaf(xk,w2.y,acc[ 9]);
            acc[10]=fmaf(xk,w2.z,acc[10]); acc[11]=fmaf(xk,w2.w,acc[11]);
            acc[12]=fmaf(xk,w3.x,acc[12]); acc[13]=fmaf(xk,w3.y,acc[13]);
            acc[14]=fmaf(xk,w3.z,acc[14]); acc[15]=fmaf(xk,w3.w,acc[15]);
        }
    }
    if (valid) {
        float sc = sdinv[r64];                  // fold dinv[src] into the row
        ushort* o = h16 + (size_t)row * 128 + c0;
        uint4 p;
        p.x = (uint)f2bf(acc[ 0]*sc) | ((uint)f2bf(acc[ 1]*sc) << 16);
        p.y = (uint)f2bf(acc[ 2]*sc) | ((uint)f2bf(acc[ 3]*sc) << 16);
        p.z = (uint)f2bf(acc[ 4]*sc) | ((uint)f2bf(acc[ 5]*sc) << 16);
        p.w = (uint)f2bf(acc[ 6]*sc) | ((uint)f2bf(acc[ 7]*sc) << 16);
        *(uint4*)(o) = p;
        p.x = (uint)f2bf(acc[ 8]*sc) | ((uint)f2bf(acc[ 9]*sc) << 16);
        p.y = (uint)f2bf(acc[10]*sc) | ((uint)f2bf(acc[11]*sc) << 16);
        p.z = (uint)f2bf(acc[12]*sc) | ((uint)f2bf(acc[13]*sc) << 16);
        p.w = (uint)f2bf(acc[14]*sc) | ((uint)f2bf(acc[15]*sc) << 16);
        *(uint4*)(o + 8) = p;
    }
}

// ---------------- GCN aggregation (dinv[src] pre-folded into h16) ----------

__launch_bounds__(256) __global__
void k_gcn(const int* __restrict__ row_off, const int2* __restrict__ csr,
           const float* __restrict__ dinv, const ushort* __restrict__ h16,
           float* __restrict__ out) {
    int lane = threadIdx.x & 63;
    int node = blockIdx.x * 4 + (threadIdx.x >> 6);
    int base = row_off[node], end = row_off[node + 1];
    float dn = dinv[node];
    int grp = lane >> 4, sl = lane & 15;
    float acc[8];
#pragma unroll
    for (int j = 0; j < 8; ++j) acc[j] = 0.f;
    int na = end - 1;
    int i0 = base + grp;
    int2 e0v = csr[imin(i0,      na)];
    int2 e1v = csr[imin(i0 + 4,  na)];
    int2 e2v = csr[imin(i0 + 8,  na)];
    int2 e3v = csr[imin(i0 + 12, na)];
    for (int i = i0; i < end; i += 16) {
        int2 p0 = csr[imin(i + 16, na)];
        int2 p1 = csr[imin(i + 20, na)];
        int2 p2 = csr[imin(i + 24, na)];
        int2 p3 = csr[imin(i + 28, na)];
        uint4 q0 = *(const uint4*)(h16 + (size_t)e0v.x * 128 + sl * 8);
        uint4 q1 = *(const uint4*)(h16 + (size_t)e1v.x * 128 + sl * 8);
        uint4 q2 = *(const uint4*)(h16 + (size_t)e2v.x * 128 + sl * 8);
        uint4 q3 = *(const uint4*)(h16 + (size_t)e3v.x * 128 + sl * 8);
        float c0 = __int_as_float(e0v.y) * dn;          // dinv[s] already in h16
        float c1 = (i + 4  < end) ? __int_as_float(e1v.y) * dn : 0.f;
        float c2 = (i + 8  < end) ? __int_as_float(e2v.y) * dn : 0.f;
        float c3 = (i + 12 < end) ? __int_as_float(e3v.y) * dn : 0.f;
        acc[0] = fmaf(c0, BLO(q0.x), fmaf(c1, BLO(q1.x), fmaf(c2, BLO(q2.x), fmaf(c3, BLO(q3.x), acc[0]))));
        acc[1] = fmaf(c0, BHI(q0.x), fmaf(c1, BHI(q1.x), fmaf(c2, BHI(q2.x), fmaf(c3, BHI(q3.x), acc[1]))));
        acc[2] = fmaf(c0, BLO(q0.y), fmaf(c1, BLO(q1.y), fmaf(c2, BLO(q2.y), fmaf(c3, BLO(q3.y), acc[2]))));
        acc[3] = fmaf(c0, BHI(q0.y), fmaf(c1, BHI(q1.y), fmaf(c2, BHI(q2.y), fmaf(c3, BHI(q3.y), acc[3]))));
        acc[4] = fmaf(c0, BLO(q0.z), fmaf(c1, BLO(q1.z), fmaf(c2, BLO(q2.z), fmaf(c3, BLO(q3.z), acc[4]))));
        acc[5] = fmaf(c0, BHI(q0.z), fmaf(c1, BHI(q1.z), fmaf(c2, BHI(q2.z), fmaf(c3, BHI(q3.z), acc[5]))));
        acc[6] = fmaf(c0, BLO(q0.w), fmaf(c1, BLO(q1.w), fmaf(c2, BLO(q2.w), fmaf(c3, BLO(q3.w), acc[6]))));
        acc[7] = fmaf(c0, BHI(q0.w), fmaf(c1, BHI(q1.w), fmaf(c2, BHI(q2.w), fmaf(c3, BHI(q3.w), acc[7]))));
        e0v = p0; e1v = p1; e2v = p2; e3v = p3;
    }
#pragma unroll
    for (int j = 0; j < 8; ++j) {
        acc[j] += __shfl_xor(acc[j], 16);
        acc[j] += __shfl_xor(acc[j], 32);
    }
    if (grp == 0) {
        float* o = out + (size_t)node * 128 + sl * 8;
        *(float4*)(o)     = make_float4(acc[0], acc[1], acc[2], acc[3]);
        *(float4*)(o + 4) = make_float4(acc[4], acc[5], acc[6], acc[7]);
    }
}

// ---------------- launch ----------------

extern "C" void kernel_launch(void* const* d_in, const int* in_sizes, int n_in,
                              void* d_out, int out_size, void* d_ws, size_t ws_size,
                              hipStream_t stream) {
    const float* x    = (const float*)d_in[0];
    const int*   ei   = (const int*)  d_in[1];   // [2,E]: src then dst
    const float* ew   = (const float*)d_in[2];
    const float* Wg   = (const float*)d_in[3];
    const float* atts = (const float*)d_in[4];
    const float* attd = (const float*)d_in[5];
    const float* Wc   = (const float*)d_in[6];
    float* out = (float*)d_out;

    float* a_s   = (float*)d_ws;             // 400000
    float* a_d   = a_s + 400000;             // 400000
    float* dinvp = a_d + 400000;             // 100000
    int* row_off = (int*)(dinvp + 100000);   // 100004
    int* bcnt    = row_off + 100004;         // NB
    int* boff    = bcnt + NB;                // NB + 1
    int* bcsr    = boff + NB + 1;            // NB
    int* bfill   = bcsr + NB;                // NB
    long long* csr = (long long*)(bfill + NB + 1);  // pad -> 8B aligned; 1.7M x 8B
    ushort* xp16 = (ushort*)(csr + 1700000);        // 12.8M bf16
    ushort* h16  = xp16 + 12800000;                 // 12.8M bf16
    long long* binned = (long long*)h16;    // alias: binned dead before h16 written

    const int* srcv = ei;
    const int* dstv = ei + EE;

    hipMemsetAsync(bcnt, 0, NB * sizeof(int), stream);
    k_bcount <<<NTILES, 256, 0, stream>>>(dstv, bcnt);
    k_bprefix<<<1, NB, 0, stream>>>(bcnt, boff, bcsr, bfill);
    k_bin    <<<NTILES, 256, 0, stream>>>(srcv, dstv, ew, bfill, binned);
    k_fine_gemm<<<NB + GEMM1_BLKS, 256, 0, stream>>>(
        binned, boff, bcsr, row_off, csr,
        x, Wg, xp16, atts, attd, a_s, a_d);
    k_gat_g2<<<GEMM_BLKS, 512, 0, stream>>>(row_off, (const int2*)csr, a_s, a_d,
                                            xp16, Wc, h16, dinvp);
    k_gcn  <<<NN / 4, 256, 0, stream>>>(row_off, (const int2*)csr, dinvp, h16, out);
}

// Round 8
// 446.568 us; speedup vs baseline: 2.4031x; 2.4031x over previous
//
#include <hip/hip_runtime.h>

#define NN 100000
#define EE 1600000
#define TOT (EE + NN)
#define NEG 0.2f
#define NB 256                      // dst buckets (one fine-block each)
#define CH 391                      // nodes per bucket = ceil(NN/NB)
#define TILE 4096                   // edges per bin block
#define NTILES ((EE + TILE - 1) / TILE)   // 391
#define GAT_BLKS ((NN + 63) / 64)   // 1563 (gat_g2 tiles of 64)
#define GEMM1_BLKS (NN / 32)        // 3125 (32 rows/block, exact: no tail)
#define LDA 132                     // LDS row stride (floats): 16B-aligned

typedef unsigned int uint;
typedef unsigned short ushort;

#define BLO(u) __uint_as_float((u) << 16)
#define BHI(u) __uint_as_float((u) & 0xffff0000u)

__device__ inline ushort f2bf(float f) {            // RNE f32 -> bf16
    uint u = __float_as_uint(f);
    return (ushort)((u + 0x7fff + ((u >> 16) & 1)) >> 16);
}

__device__ inline int imin(int a, int b) { return a < b ? a : b; }

// ---------------- bucket count ----------------

__launch_bounds__(256) __global__
void k_bcount(const int* __restrict__ dst, int* __restrict__ bcnt) {
    __shared__ int h[NB];
    int t = threadIdx.x;
    h[t] = 0;
    __syncthreads();
    int base = blockIdx.x * TILE;
#pragma unroll
    for (int r = 0; r < 16; ++r) {
        int e = base + r * 256 + t;
        if (e < EE) atomicAdd(&h[dst[e] / CH], 1);
    }
    __syncthreads();
    if (h[t]) atomicAdd(&bcnt[t], h[t]);
}

// ---------------- bucket prefix (1 block) ----------------

__launch_bounds__(NB) __global__
void k_bprefix(const int* __restrict__ bcnt, int* __restrict__ boff,
               int* __restrict__ bcsr, int* __restrict__ bfill) {
    __shared__ int s1[NB], s2[NB];
    int t = threadIdx.x;
    int c = bcnt[t];
    int nb0 = t * CH;
    int nib = imin(nb0 + CH, NN) - nb0;     // nodes in this bucket
    s1[t] = c; s2[t] = c + nib;
    __syncthreads();
    for (int off = 1; off < NB; off <<= 1) {
        int a = (t >= off) ? s1[t - off] : 0;
        int b = (t >= off) ? s2[t - off] : 0;
        __syncthreads();
        s1[t] += a; s2[t] += b;
        __syncthreads();
    }
    int ex = s1[t] - c;
    boff[t] = ex;
    bfill[t] = ex;
    bcsr[t] = s2[t] - (c + nib);
    if (t == NB - 1) boff[NB] = EE;
}

// ---------------- bin pass: LDS multi-split, coalesced global writes --------

__launch_bounds__(256) __global__
void k_bin(const int* __restrict__ src, const int* __restrict__ dst,
           const float* __restrict__ ew, int* __restrict__ bfill,
           long long* __restrict__ binned) {
    __shared__ long long recs[TILE];   // 32 KB, bucket-ordered staging
    __shared__ ushort    bkt[TILE];    // 8 KB
    __shared__ int hist[NB], eoff[NB], gbase[NB];
    int t = threadIdx.x;
    hist[t] = 0;
    __syncthreads();
    int base = blockIdx.x * TILE;
    int cnt = imin(TILE, EE - base);
    long long rec[16]; int binfo[16];
#pragma unroll
    for (int r = 0; r < 16; ++r) {
        int i = r * 256 + t;
        if (i < cnt) {
            int e = base + i;
            int s = src[e], d = dst[e];
            float w = ew[e];
            int b = d / CH;
            int ldst = d - b * CH;
            int rk = atomicAdd(&hist[b], 1);          // LDS atomic = within-tile rank
            rec[r] = (long long)(uint)(s | (ldst << 17)) |
                     ((long long)__float_as_uint(w) << 32);
            binfo[r] = b | (rk << 8);
        }
    }
    __syncthreads();
    int c = hist[t];
    eoff[t] = c;
    __syncthreads();
    for (int off = 1; off < NB; off <<= 1) {          // inclusive scan
        int a = (t >= off) ? eoff[t - off] : 0;
        __syncthreads();
        eoff[t] += a;
        __syncthreads();
    }
    int ex = eoff[t] - c;                             // own exclusive offset
    gbase[t] = atomicAdd(&bfill[t], c);               // reserve contiguous chunk
    eoff[t] = ex;
    __syncthreads();
#pragma unroll
    for (int r = 0; r < 16; ++r) {                    // stage bucket-ordered in LDS
        int i = r * 256 + t;
        if (i < cnt) {
            int b = binfo[r] & 255, rk = binfo[r] >> 8;
            int slot = eoff[b] + rk;
            recs[slot] = rec[r];
            bkt[slot] = (ushort)b;
        }
    }
    __syncthreads();
#pragma unroll
    for (int r = 0; r < 16; ++r) {                    // coalesced runs (~128B/bucket)
        int i = r * 256 + t;
        if (i < cnt) {
            int b = bkt[i];
            binned[gbase[b] + (i - eoff[b])] = recs[i];
        }
    }
}

// ---------------- gemm1: 32 rows/block, lane-owns-2-cols, A staged in LDS ----
// Round-7 lesson: col-seg-per-lane (16 cols/lane) issued 512 VMEM/thread with
// 8x duplicated addresses -> L1 thrash, 0.76 TB/s. This mapping: lane owns
// cols (2*lane, 2*lane+1); per k ONE float2/lane = the wave covers the 512B
// W row exactly once, zero duplication, 128 VMEM/thread, k-sequential stream.
// A broadcast from LDS (wave-uniform b128). Replaces the scalar-unit-bound
// s_load W stream (1 scalar unit/CU serialized all 32 waves). Per-output
// fmaf chain stays k-ascending -> xp16 bit-identical.

__device__ __forceinline__ void gemm1_body(
    int bid, const float* __restrict__ A, const float* __restrict__ W,
    ushort* __restrict__ C16, const float* __restrict__ att_s,
    const float* __restrict__ att_d, float* __restrict__ a_s,
    float* __restrict__ a_d, float* __restrict__ At) {
    int t = threadIdx.x;
    int lane = t & 63, wv = t >> 6;         // 4 waves
    int rbase = bid * 32;                   // 3125*32 == NN: no tail
    // stage A tile: 32 rows x 128 f32 = 16 KB, coalesced float4
    const float4* Ag = (const float4*)(A + (size_t)rbase * 128);
    float4* At4 = (float4*)At;
#pragma unroll
    for (int i = 0; i < 4; ++i) At4[i * 256 + t] = Ag[i * 256 + t];
    __syncthreads();
    int r0 = wv * 8;                        // wave owns 8 rows
    int c0 = lane * 2;                      // lane owns 2 adjacent cols
    const float* wp = W + c0;
    float acc[8][2];
#pragma unroll
    for (int r = 0; r < 8; ++r) { acc[r][0] = 0.f; acc[r][1] = 0.f; }
    for (int k = 0; k < 128; k += 4) {
        float2 w0 = *(const float2*)(wp + (k + 0) * 128);
        float2 w1 = *(const float2*)(wp + (k + 1) * 128);
        float2 w2 = *(const float2*)(wp + (k + 2) * 128);
        float2 w3 = *(const float2*)(wp + (k + 3) * 128);
#pragma unroll
        for (int r = 0; r < 8; ++r) {
            float4 av = *(const float4*)(At + (r0 + r) * 128 + k);
            acc[r][0] = fmaf(av.w, w3.x, fmaf(av.z, w2.x, fmaf(av.y, w1.x, fmaf(av.x, w0.x, acc[r][0]))));
            acc[r][1] = fmaf(av.w, w3.y, fmaf(av.z, w2.y, fmaf(av.y, w1.y, fmaf(av.x, w0.y, acc[r][1]))));
        }
    }
    // stores (wave covers a full 256B bf16 row) + logit epilogue
    float as0 = att_s[c0], as1 = att_s[c0 + 1];   // att layout [4][32] = flat 128
    float ad0 = att_d[c0], ad1 = att_d[c0 + 1];
    int head = lane >> 4;                   // lanes 16h..16h+15 <-> cols 32h..+31
#pragma unroll
    for (int r = 0; r < 8; ++r) {
        int row = rbase + r0 + r;
        uint pv = (uint)f2bf(acc[r][0]) | ((uint)f2bf(acc[r][1]) << 16);
        *(uint*)(C16 + (size_t)row * 128 + c0) = pv;
        float s0 = fmaf(acc[r][1], as1, acc[r][0] * as0);
        float s1 = fmaf(acc[r][1], ad1, acc[r][0] * ad0);
        s0 += __shfl_xor(s0, 1); s0 += __shfl_xor(s0, 2);
        s0 += __shfl_xor(s0, 4); s0 += __shfl_xor(s0, 8);
        s1 += __shfl_xor(s1, 1); s1 += __shfl_xor(s1, 2);
        s1 += __shfl_xor(s1, 4); s1 += __shfl_xor(s1, 8);
        if ((lane & 15) == 0) {
            a_s[row * 4 + head] = s0;
            a_d[row * 4 + head] = s1;
        }
    }
}

// ---------------- fused: fine scatter (L2-resident per bucket) + gemm1 ------

__launch_bounds__(256) __global__
void k_fine_gemm(const long long* __restrict__ binned, const int* __restrict__ boff,
                 const int* __restrict__ bcsr, int* __restrict__ row_off,
                 long long* __restrict__ csr,
                 const float* __restrict__ A, const float* __restrict__ W,
                 ushort* __restrict__ C16, const float* __restrict__ att_s,
                 const float* __restrict__ att_d, float* __restrict__ a_s,
                 float* __restrict__ a_d) {
    __shared__ int smem[4096];              // 16 KB: A-tile (gemm) / scan (fine)
    if (blockIdx.x >= NB) {
        gemm1_body(blockIdx.x - NB, A, W, C16, att_s, att_d, a_s, a_d,
                   (float*)smem);
        return;
    }
    int* hist = smem;                       // [CH]
    int* excl = smem + 400;                 // [CH]
    int* sc   = smem + 800;                 // [512]
    int t = threadIdx.x;
    int b = blockIdx.x;
    int e0 = boff[b], e1 = boff[b + 1];
    int nb0 = b * CH;
    int nnode = imin(CH, NN - nb0);
    const int2* __restrict__ bn = (const int2*)binned;
    hist[t] = 0;
    if (t + 256 < CH) hist[t + 256] = 0;
    __syncthreads();
    for (int i = e0 + t; i < e1; i += 256)            // pass 1: per-node counts
        atomicAdd(&hist[bn[i].x >> 17], 1);
    __syncthreads();
    int v0 = (t < nnode) ? hist[t] + 1 : 0;           // +1 self-loop
    int v1 = (t + 256 < nnode) ? hist[t + 256] + 1 : 0;
    sc[t] = v0; sc[t + 256] = v1;
    __syncthreads();
    for (int off = 1; off < 512; off <<= 1) {         // Hillis-Steele, 2 elems/thread
        int a0 = (t >= off) ? sc[t - off] : 0;
        int a1 = (t + 256 >= off) ? sc[t + 256 - off] : 0;
        __syncthreads();
        sc[t] += a0; sc[t + 256] += a1;
        __syncthreads();
    }
    int csr0 = bcsr[b];
    if (t < nnode) {
        excl[t] = csr0 + sc[t] - v0;
        row_off[nb0 + t] = excl[t];
    }
    if (t + 256 < nnode) {
        excl[t + 256] = csr0 + sc[t + 256] - v1;
        row_off[nb0 + t + 256] = excl[t + 256];
    }
    if (b == 0 && t == 0) row_off[NN] = TOT;
    hist[t] = 0;                                      // reset -> rank counters
    if (t + 256 < CH) hist[t + 256] = 0;
    __syncthreads();
    for (int i = e0 + t; i < e1; i += 256) {          // pass 2: L2-window scatter
        int2 r = bn[i];
        int ld = r.x >> 17;
        int rk = atomicAdd(&hist[ld], 1);
        long long rec = (long long)(uint)(r.x & 0x1FFFF) |
                        ((long long)(uint)r.y << 32);
        csr[excl[ld] + rk] = rec;
    }
    __syncthreads();
    for (int i = t; i < nnode; i += 256) {            // self-loops at row end, w = 1
        int n = nb0 + i;
        csr[excl[i] + hist[i]] = (long long)(uint)n | (0x3F800000LL << 32);
    }
}

// ---------------- fused GAT aggregation + GEMM2 (512-thread blocks) ----------
// Phase 1: round-5 structure (best measured gather config for the fusion).
// Phase 2: lane-owns-2-cols GEMM (see gemm1_body comment); A from the LDS
// tile; coalesced W float2 stream; full-row coalesced h16 stores.

__launch_bounds__(512) __global__
void k_gat_g2(const int* __restrict__ row_off, const int2* __restrict__ csr,
              const float* __restrict__ a_s, const float* __restrict__ a_d,
              const ushort* __restrict__ xp16, const float* __restrict__ W,
              ushort* __restrict__ h16, float* __restrict__ dinv) {
    __shared__ float As[64 * LDA];
    __shared__ float sdinv[64];
    int lane = threadIdx.x & 63;
    int wv = threadIdx.x >> 6;              // 0..7
    int grp = lane >> 4, sl = lane & 15, h2 = sl >> 2;
    int nbase = blockIdx.x * 64;

    for (int rnd = 0; rnd < 8; ++rnd) {
        int r = (rnd << 3) | wv;            // row in block, 0..63
        int node = nbase + r;
        if (node < NN) {
            int base = row_off[node], end = row_off[node + 1];
            float adh = a_d[node * 4 + h2];
            float acc[8];
#pragma unroll
            for (int j = 0; j < 8; ++j) acc[j] = 0.f;
            float den = 0.f, wsum = 0.f;
            int na = end - 1;
            int i0 = base + grp;
            int2 e0v = csr[imin(i0,      na)];
            int2 e1v = csr[imin(i0 + 4,  na)];
            int2 e2v = csr[imin(i0 + 8,  na)];
            int2 e3v = csr[imin(i0 + 12, na)];
            for (int i = i0; i < end; i += 16) {
                int2 p0 = csr[imin(i + 16, na)];        // prefetch next trip
                int2 p1 = csr[imin(i + 20, na)];
                int2 p2 = csr[imin(i + 24, na)];
                int2 p3 = csr[imin(i + 28, na)];
                uint4 q0 = *(const uint4*)(xp16 + (size_t)e0v.x * 128 + sl * 8);
                uint4 q1 = *(const uint4*)(xp16 + (size_t)e1v.x * 128 + sl * 8);
                uint4 q2 = *(const uint4*)(xp16 + (size_t)e2v.x * 128 + sl * 8);
                uint4 q3 = *(const uint4*)(xp16 + (size_t)e3v.x * 128 + sl * 8);
                float al0 = a_s[e0v.x * 4 + h2] + adh;
                float al1 = a_s[e1v.x * 4 + h2] + adh;
                float al2 = a_s[e2v.x * 4 + h2] + adh;
                float al3 = a_s[e3v.x * 4 + h2] + adh;
                al0 = al0 > 0.f ? al0 : NEG * al0;
                al1 = al1 > 0.f ? al1 : NEG * al1;
                al2 = al2 > 0.f ? al2 : NEG * al2;
                al3 = al3 > 0.f ? al3 : NEG * al3;
                float aw0 = __expf(al0);                     // i < end always
                float aw1 = (i + 4  < end) ? __expf(al1) : 0.f;
                float aw2 = (i + 8  < end) ? __expf(al2) : 0.f;
                float aw3 = (i + 12 < end) ? __expf(al3) : 0.f;
                float w0 = __int_as_float(e0v.y);
                float w1 = (i + 4  < end) ? __int_as_float(e1v.y) : 0.f;
                float w2 = (i + 8  < end) ? __int_as_float(e2v.y) : 0.f;
                float w3 = (i + 12 < end) ? __int_as_float(e3v.y) : 0.f;
                den  += (aw0 + aw1) + (aw2 + aw3);
                wsum += (w0 + w1) + (w2 + w3);
                acc[0] = fmaf(aw0, BLO(q0.x), fmaf(aw1, BLO(q1.x), fmaf(aw2, BLO(q2.x), fmaf(aw3, BLO(q3.x), acc[0]))));
                acc[1] = fmaf(aw0, BHI(q0.x), fmaf(aw1, BHI(q1.x), fmaf(aw2, BHI(q2.x), fmaf(aw3, BHI(q3.x), acc[1]))));
                acc[2] = fmaf(aw0, BLO(q0.y), fmaf(aw1, BLO(q1.y), fmaf(aw2, BLO(q2.y), fmaf(aw3, BLO(q3.y), acc[2]))));
                acc[3] = fmaf(aw0, BHI(q0.y), fmaf(aw1, BHI(q1.y), fmaf(aw2, BHI(q2.y), fmaf(aw3, BHI(q3.y), acc[3]))));
                acc[4] = fmaf(aw0, BLO(q0.z), fmaf(aw1, BLO(q1.z), fmaf(aw2, BLO(q2.z), fmaf(aw3, BLO(q3.z), acc[4]))));
                acc[5] = fmaf(aw0, BHI(q0.z), fmaf(aw1, BHI(q1.z), fmaf(aw2, BHI(q2.z), fmaf(aw3, BHI(q3.z), acc[5]))));
                acc[6] = fmaf(aw0, BLO(q0.w), fmaf(aw1, BLO(q1.w), fmaf(aw2, BLO(q2.w), fmaf(aw3, BLO(q3.w), acc[6]))));
                acc[7] = fmaf(aw0, BHI(q0.w), fmaf(aw1, BHI(q1.w), fmaf(aw2, BHI(q2.w), fmaf(aw3, BHI(q3.w), acc[7]))));
                e0v = p0; e1v = p1; e2v = p2; e3v = p3;
            }
#pragma unroll
            for (int j = 0; j < 8; ++j) {
                acc[j] += __shfl_xor(acc[j], 16);
                acc[j] += __shfl_xor(acc[j], 32);
            }
            den  += __shfl_xor(den, 16);   den  += __shfl_xor(den, 32);
            wsum += __shfl_xor(wsum, 16);  wsum += __shfl_xor(wsum, 32);
            if (grp == 0) {
                float il = 1.f / den;
                float* o = &As[r * LDA + sl * 8];
                *(float4*)(o)     = make_float4(acc[0]*il, acc[1]*il, acc[2]*il, acc[3]*il);
                *(float4*)(o + 4) = make_float4(acc[4]*il, acc[5]*il, acc[6]*il, acc[7]*il);
                if (sl == 0) {
                    float dv = rsqrtf(wsum);
                    sdinv[r] = dv;
                    dinv[node] = dv;        // k_gcn needs the dst-side factor
                }
            }
        } else if (grp == 0) {              // tail block: zero-fill invalid rows
            float* o = &As[r * LDA + sl * 8];
            *(float4*)(o)     = make_float4(0.f, 0.f, 0.f, 0.f);
            *(float4*)(o + 4) = make_float4(0.f, 0.f, 0.f, 0.f);
            if (sl == 0) sdinv[r] = 0.f;
        }
    }
    __syncthreads();

    // ---- phase 2: gemm2, lane-owns-2-cols; wave wv owns rows wv*8..+8 ----
    int r0 = wv * 8;
    int c0 = lane * 2;
    const float* __restrict__ wp = W + c0;
    float acc2[8][2];
#pragma unroll
    for (int r = 0; r < 8; ++r) { acc2[r][0] = 0.f; acc2[r][1] = 0.f; }
    for (int k = 0; k < 128; k += 4) {
        float2 w0 = *(const float2*)(wp + (k + 0) * 128);
        float2 w1 = *(const float2*)(wp + (k + 1) * 128);
        float2 w2 = *(const float2*)(wp + (k + 2) * 128);
        float2 w3 = *(const float2*)(wp + (k + 3) * 128);
#pragma unroll
        for (int r = 0; r < 8; ++r) {
            float4 av = *(const float4*)(&As[(r0 + r) * LDA + k]);
            acc2[r][0] = fmaf(av.w, w3.x, fmaf(av.z, w2.x, fmaf(av.y, w1.x, fmaf(av.x, w0.x, acc2[r][0]))));
            acc2[r][1] = fmaf(av.w, w3.y, fmaf(av.z, w2.y, fmaf(av.y, w1.y, fmaf(av.x, w0.y, acc2[r][1]))));
        }
    }
#pragma unroll
    for (int r = 0; r < 8; ++r) {
        int row = nbase + r0 + r;
        if (row < NN) {
            float sc2 = sdinv[r0 + r];          // fold dinv[src] into the row
            uint pv = (uint)f2bf(acc2[r][0] * sc2) |
                      ((uint)f2bf(acc2[r][1] * sc2) << 16);
            *(uint*)(h16 + (size_t)row * 128 + c0) = pv;
        }
    }
}

// ---------------- GCN aggregation (dinv[src] pre-folded into h16) ----------
// Same 4-deep MLP as k_gat_g2 phase 1.

__launch_bounds__(256) __global__
void k_gcn(const int* __restrict__ row_off, const int2* __restrict__ csr,
           const float* __restrict__ dinv, const ushort* __restrict__ h16,
           float* __restrict__ out) {
    int lane = threadIdx.x & 63;
    int node = blockIdx.x * 4 + (threadIdx.x >> 6);
    int base = row_off[node], end = row_off[node + 1];
    float dn = dinv[node];
    int grp = lane >> 4, sl = lane & 15;
    float acc[8];
#pragma unroll
    for (int j = 0; j < 8; ++j) acc[j] = 0.f;
    int na = end - 1;
    int i0 = base + grp;
    int2 e0v = csr[imin(i0,      na)];
    int2 e1v = csr[imin(i0 + 4,  na)];
    int2 e2v = csr[imin(i0 + 8,  na)];
    int2 e3v = csr[imin(i0 + 12, na)];
    for (int i = i0; i < end; i += 16) {
        int2 p0 = csr[imin(i + 16, na)];
        int2 p1 = csr[imin(i + 20, na)];
        int2 p2 = csr[imin(i + 24, na)];
        int2 p3 = csr[imin(i + 28, na)];
        uint4 q0 = *(const uint4*)(h16 + (size_t)e0v.x * 128 + sl * 8);
        uint4 q1 = *(const uint4*)(h16 + (size_t)e1v.x * 128 + sl * 8);
        uint4 q2 = *(const uint4*)(h16 + (size_t)e2v.x * 128 + sl * 8);
        uint4 q3 = *(const uint4*)(h16 + (size_t)e3v.x * 128 + sl * 8);
        float c0 = __int_as_float(e0v.y) * dn;          // dinv[s] already in h16
        float c1 = (i + 4  < end) ? __int_as_float(e1v.y) * dn : 0.f;
        float c2 = (i + 8  < end) ? __int_as_float(e2v.y) * dn : 0.f;
        float c3 = (i + 12 < end) ? __int_as_float(e3v.y) * dn : 0.f;
        acc[0] = fmaf(c0, BLO(q0.x), fmaf(c1, BLO(q1.x), fmaf(c2, BLO(q2.x), fmaf(c3, BLO(q3.x), acc[0]))));
        acc[1] = fmaf(c0, BHI(q0.x), fmaf(c1, BHI(q1.x), fmaf(c2, BHI(q2.x), fmaf(c3, BHI(q3.x), acc[1]))));
        acc[2] = fmaf(c0, BLO(q0.y), fmaf(c1, BLO(q1.y), fmaf(c2, BLO(q2.y), fmaf(c3, BLO(q3.y), acc[2]))));
        acc[3] = fmaf(c0, BHI(q0.y), fmaf(c1, BHI(q1.y), fmaf(c2, BHI(q2.y), fmaf(c3, BHI(q3.y), acc[3]))));
        acc[4] = fmaf(c0, BLO(q0.z), fmaf(c1, BLO(q1.z), fmaf(c2, BLO(q2.z), fmaf(c3, BLO(q3.z), acc[4]))));
        acc[5] = fmaf(c0, BHI(q0.z), fmaf(c1, BHI(q1.z), fmaf(c2, BHI(q2.z), fmaf(c3, BHI(q3.z), acc[5]))));
        acc[6] = fmaf(c0, BLO(q0.w), fmaf(c1, BLO(q1.w), fmaf(c2, BLO(q2.w), fmaf(c3, BLO(q3.w), acc[6]))));
        acc[7] = fmaf(c0, BHI(q0.w), fmaf(c1, BHI(q1.w), fmaf(c2, BHI(q2.w), fmaf(c3, BHI(q3.w), acc[7]))));
        e0v = p0; e1v = p1; e2v = p2; e3v = p3;
    }
#pragma unroll
    for (int j = 0; j < 8; ++j) {
        acc[j] += __shfl_xor(acc[j], 16);
        acc[j] += __shfl_xor(acc[j], 32);
    }
    if (grp == 0) {
        float* o = out + (size_t)node * 128 + sl * 8;
        *(float4*)(o)     = make_float4(acc[0], acc[1], acc[2], acc[3]);
        *(float4*)(o + 4) = make_float4(acc[4], acc[5], acc[6], acc[7]);
    }
}

// ---------------- launch ----------------

extern "C" void kernel_launch(void* const* d_in, const int* in_sizes, int n_in,
                              void* d_out, int out_size, void* d_ws, size_t ws_size,
                              hipStream_t stream) {
    const float* x    = (const float*)d_in[0];
    const int*   ei   = (const int*)  d_in[1];   // [2,E]: src then dst
    const float* ew   = (const float*)d_in[2];
    const float* Wg   = (const float*)d_in[3];
    const float* atts = (const float*)d_in[4];
    const float* attd = (const float*)d_in[5];
    const float* Wc   = (const float*)d_in[6];
    float* out = (float*)d_out;

    float* a_s   = (float*)d_ws;             // 400000
    float* a_d   = a_s + 400000;             // 400000
    float* dinvp = a_d + 400000;             // 100000
    int* row_off = (int*)(dinvp + 100000);   // 100004
    int* bcnt    = row_off + 100004;         // NB
    int* boff    = bcnt + NB;                // NB + 1
    int* bcsr    = boff + NB + 1;            // NB
    int* bfill   = bcsr + NB;                // NB
    long long* csr = (long long*)(bfill + NB + 1);  // pad -> 8B aligned; 1.7M x 8B
    ushort* xp16 = (ushort*)(csr + 1700000);        // 12.8M bf16
    ushort* h16  = xp16 + 12800000;                 // 12.8M bf16
    long long* binned = (long long*)h16;    // alias: binned dead before h16 written

    const int* srcv = ei;
    const int* dstv = ei + EE;

    hipMemsetAsync(bcnt, 0, NB * sizeof(int), stream);
    k_bcount <<<NTILES, 256, 0, stream>>>(dstv, bcnt);
    k_bprefix<<<1, NB, 0, stream>>>(bcnt, boff, bcsr, bfill);
    k_bin    <<<NTILES, 256, 0, stream>>>(srcv, dstv, ew, bfill, binned);
    k_fine_gemm<<<NB + GEMM1_BLKS, 256, 0, stream>>>(
        binned, boff, bcsr, row_off, csr,
        x, Wg, xp16, atts, attd, a_s, a_d);
    k_gat_g2<<<GAT_BLKS, 512, 0, stream>>>(row_off, (const int2*)csr, a_s, a_d,
                                           xp16, Wc, h16, dinvp);
    k_gcn  <<<NN / 4, 256, 0, stream>>>(row_off, (const int2*)csr, dinvp, h16, out);
}